// Round 1
// baseline (256.079 us; speedup 1.0000x reference)
//
#include <hip/hip_runtime.h>
#include <math.h>

#define NL 1024      // N_LEVELS
#define KP1 9        // K+1

// ---------------------------------------------------------------------------
// Kernel 1: precompute out_table[nidx] for all 1024 levels.
// Replicates the reference's fp32 op sequence exactly:
//   v = grid[nidx]; for t=1..8: z=(v-T[t]>=0); out+=z*d[t]; v=h[nidx,t+1];
//   out -= b
// ---------------------------------------------------------------------------
__global__ __launch_bounds__(256) void build_table_kernel(
    const float* __restrict__ h,   // (NL, KP1) row-major
    const float* __restrict__ d,   // (KP1,)
    const float* __restrict__ T,   // (KP1,)
    const float* __restrict__ bp,  // scalar
    float* __restrict__ table)     // (NL,) out
{
    int i = blockIdx.x * blockDim.x + threadIdx.x;
    if (i >= NL) return;
    float v = h[i * KP1 + 0];
    float out = 0.0f;
    float b = bp[0];
#pragma unroll
    for (int t = 1; t <= 8; ++t) {
        // exact replication: subtract, then compare to 0 (handles -0.0 edge)
        float z = ((v - T[t]) >= 0.0f) ? 1.0f : 0.0f;
        out = out + z * d[t];
        if (t != 8) v = h[i * KP1 + (t + 1)];
    }
    table[i] = out - b;
}

// Swizzle for the binary-search LDS array: +1 pad every 32 elements so that
// power-of-2 strides (512/256/128/64/32) map to distinct banks instead of all
// landing on bank (i%32). sg[swz(i)] holds grid[i].
__device__ __forceinline__ int swz(int i) { return i + (i >> 5); }

// ---------------------------------------------------------------------------
// Kernel 2: main elementwise kernel.
//   searchsorted(grid, x, side='left')  -> branchless 10-step lower_bound
//   idx = clip(.., 1, 1023)
//   quad[idx] = {grid[idx-1], grid[idx], table[idx-1], table[idx]}  (b128)
//   out = (|x-left| < |x-right|) ? table[idx-1] : table[idx]
// ---------------------------------------------------------------------------
__global__ __launch_bounds__(256) void ps_act_kernel(
    const float* __restrict__ x,
    const float* __restrict__ h,      // (NL, KP1): grid = h[i*KP1]
    const float* __restrict__ table,  // (NL,) from kernel 1 (in d_ws)
    float* __restrict__ out,
    int n4)                           // number of float4 elements
{
    __shared__ float  sg[NL + NL / 32];  // swizzled grid, 4.2 KB
    __shared__ float4 qd[NL];            // fused left/right/tabL/tabR, 16 KB

    // Stage grid + quad table. h (36 KB) and table (4 KB) are L2-resident.
    for (int i = threadIdx.x; i < NL; i += blockDim.x) {
        float g = h[i * KP1];
        sg[swz(i)] = g;
        float gm1 = (i > 0) ? h[(i - 1) * KP1] : 0.0f;
        float tm1 = (i > 0) ? table[i - 1] : 0.0f;
        qd[i] = make_float4(gm1, g, tm1, table[i]);
    }
    __syncthreads();

    const float4* __restrict__ x4 = (const float4*)x;
    float4* __restrict__ o4 = (float4*)out;
    const int stride = gridDim.x * blockDim.x;

    for (int i4 = blockIdx.x * blockDim.x + threadIdx.x; i4 < n4; i4 += stride) {
        float4 xv = x4[i4];
        float xin[4] = {xv.x, xv.y, xv.z, xv.w};
        float xo[4];
#pragma unroll
        for (int e = 0; e < 4; ++e) {
            float xf = xin[e];
            // lower_bound: lo = count of grid[i] < xf  (== searchsorted left)
            int lo = 0;
#pragma unroll
            for (int s = 512; s >= 1; s >>= 1) {
                float v = sg[swz(lo + s - 1)];
                if (v < xf) lo += s;
            }
            int idx = lo < 1 ? 1 : (lo > NL - 1 ? NL - 1 : lo);
            float4 q = qd[idx];
            float dl = fabsf(xf - q.x);   // exact same fp32 ops as reference
            float dr = fabsf(xf - q.y);
            xo[e] = (dl < dr) ? q.z : q.w;
        }
        o4[i4] = make_float4(xo[0], xo[1], xo[2], xo[3]);
    }
}

extern "C" void kernel_launch(void* const* d_in, const int* in_sizes, int n_in,
                              void* d_out, int out_size, void* d_ws, size_t ws_size,
                              hipStream_t stream) {
    const float* x = (const float*)d_in[0];
    const float* h = (const float*)d_in[1];
    const float* d = (const float*)d_in[2];
    const float* T = (const float*)d_in[3];
    const float* b = (const float*)d_in[4];
    float* out = (float*)d_out;
    float* table = (float*)d_ws;   // 4 KB of workspace, rebuilt every call

    int n = in_sizes[0];
    int n4 = n / 4;                // n = 64*512*1024, divisible by 4

    build_table_kernel<<<(NL + 255) / 256, 256, 0, stream>>>(h, d, T, b, table);

    // 2048 blocks: ~16 float4 iters/thread, setup (2K cached loads/block)
    // amortized over 16K elements/block. LDS 20.2 KB -> 7 blocks/CU resident.
    ps_act_kernel<<<2048, 256, 0, stream>>>(x, h, table, out, n4);
}

// Round 2
// 253.786 us; speedup vs baseline: 1.0090x; 1.0090x over previous
//
#include <hip/hip_runtime.h>
#include <math.h>

#define NL  1024     // N_LEVELS
#define KP1 9        // K+1
#define NB  8192     // direct-mapped buckets

// d_ws float layout:
//   [0]=lo0  [1]=inv  [2..3] pad
//   [WS_TAB .. +1024)  out-value table per level
//   [WS_BS  .. +1032)  1023 fp32 decision boundaries + 9 INF pads
//   [WS_BKT .. +4096)  8192 x u16 bucket->start-count table
#define WS_TAB 4
#define WS_BS  1028
#define WS_BKT 2060   // byte offset 8240, total ws use ~24.7 KB

// order-preserving float<->uint map (total order incl. negatives)
__device__ __forceinline__ unsigned oi(float f) {
    unsigned u = __float_as_uint(f);
    return (u & 0x80000000u) ? ~u : (u | 0x80000000u);
}
__device__ __forceinline__ float unoi(unsigned k) {
    return __uint_as_float((k & 0x80000000u) ? (k & 0x7fffffffu) : ~k);
}

// bucket index — MUST be the identical fp32 op sequence in build and main
// kernels (monotone: fp sub/mul-by-positive/trunc/clamp are all monotone).
__device__ __forceinline__ int bidx(float x, float lo0, float inv) {
    float t = (x - lo0) * inv;
    int j = (int)t;              // trunc toward zero; clamped below anyway
    j = j < 0 ? 0 : j;
    j = j > (NB - 1) ? (NB - 1) : j;
    return j;
}

// ---------------------------------------------------------------------------
// Build kernel (1 block, 1024 threads):
//  1. tab[i]  = reference threshold-chain output for level i (exact replica)
//  2. B[i]    = smallest fp32 x where pair (i,i+1) chooses RIGHT, via bit-level
//               binary search of the exact reference predicate !(|x-l|<|x-r|)
//  3. bucket[j] = #{ i : bidx(B[i]) < j }   (u16, searchsorted start counts)
// ---------------------------------------------------------------------------
__global__ __launch_bounds__(1024) void build_kernel(
    const float* __restrict__ h, const float* __restrict__ d,
    const float* __restrict__ T, const float* __restrict__ bp,
    float* __restrict__ ws)
{
    __shared__ float s_g[NL];
    __shared__ float s_B[NL];     // 1023 boundaries + [1023]=INF
    __shared__ int   s_jb[NL];    // bidx of each boundary + sentinel
    __shared__ float s_lo0, s_inv;

    const int tid = threadIdx.x;
    float g = h[tid * KP1];
    s_g[tid] = g;

    // 1. out-value table (exact replica of reference fp32 sequence)
    {
        float v = g, outv = 0.0f, b = bp[0];
#pragma unroll
        for (int t = 1; t <= 8; ++t) {
            float z = ((v - T[t]) >= 0.0f) ? 1.0f : 0.0f;
            outv = outv + z * d[t];
            if (t != 8) v = h[tid * KP1 + (t + 1)];
        }
        ws[WS_TAB + tid] = outv - b;
    }
    __syncthreads();

    // 2. exact fp32 decision boundary per adjacent pair
    if (tid < NL - 1) {
        float l = s_g[tid], r = s_g[tid + 1];
        unsigned a = oi(l), b2 = oi(r);   // predicate false at l, true at r
        while (a < b2) {
            unsigned m = a + ((b2 - a) >> 1);
            float xm = unoi(m);
            float dl = fabsf(xm - l), dr = fabsf(xm - r);
            if (!(dl < dr)) b2 = m; else a = m + 1;
        }
        s_B[tid] = unoi(a);
    } else {
        s_B[tid] = INFINITY;
    }
    __syncthreads();

    if (tid == 0) {
        float lo0 = s_B[0];
        float inv = (float)NB / (s_B[NL - 2] - lo0);
        s_lo0 = lo0; s_inv = inv;
        ws[0] = lo0; ws[1] = inv;
    }
    __syncthreads();

    float lo0 = s_lo0, inv = s_inv;
    s_jb[tid] = (tid < NL - 1) ? bidx(s_B[tid], lo0, inv) : 0x7fffffff;
    ws[WS_BS + tid] = s_B[tid];                       // [1023] = INF
    if (tid < 8) ws[WS_BS + NL + tid] = INFINITY;     // scan-overrun pads
    __syncthreads();

    // 3. bucket start counts: lower_bound over sorted s_jb
    unsigned short* bucket = (unsigned short*)(ws + WS_BKT);
    for (int j = tid; j < NB; j += 1024) {
        int lo = 0;
#pragma unroll
        for (int s = 512; s >= 1; s >>= 1)
            if (s_jb[lo + s - 1] < j) lo += s;
        bucket[j] = (unsigned short)lo;
    }
}

// ---------------------------------------------------------------------------
// Main kernel: per element — bucket lookup, ~0.1-step scan, table read.
// ---------------------------------------------------------------------------
__global__ __launch_bounds__(256) void ps_act_kernel(
    const float* __restrict__ x,
    const float* __restrict__ ws,
    float* __restrict__ out,
    int n4)
{
    __shared__ float          stab[NL];
    __shared__ float          sBs[NL + 8];
    __shared__ unsigned short sbk[NB];

    const int tid = threadIdx.x;
    for (int i = tid; i < NL; i += 256)     stab[i] = ws[WS_TAB + i];
    for (int i = tid; i < NL + 8; i += 256) sBs[i]  = ws[WS_BS + i];
    const unsigned short* gbk = (const unsigned short*)(ws + WS_BKT);
    for (int i = tid; i < NB; i += 256)     sbk[i]  = gbk[i];
    const float lo0 = ws[0];
    const float inv = ws[1];
    __syncthreads();

    const float4* __restrict__ x4 = (const float4*)x;
    float4* __restrict__ o4 = (float4*)out;
    const int stride = gridDim.x * blockDim.x;

    for (int i4 = blockIdx.x * blockDim.x + tid; i4 < n4; i4 += stride) {
        float4 xv = x4[i4];
        float xin[4] = {xv.x, xv.y, xv.z, xv.w};
        float xo[4];
#pragma unroll
        for (int e = 0; e < 4; ++e) {
            float xf = xin[e];
            int j = bidx(xf, lo0, inv);
            int ni = sbk[j];
            // average ~0.1 iterations; INF pads guarantee termination
            while (sBs[ni] <= xf) ++ni;
            xo[e] = stab[ni];
        }
        o4[i4] = make_float4(xo[0], xo[1], xo[2], xo[3]);
    }
}

extern "C" void kernel_launch(void* const* d_in, const int* in_sizes, int n_in,
                              void* d_out, int out_size, void* d_ws, size_t ws_size,
                              hipStream_t stream) {
    const float* x = (const float*)d_in[0];
    const float* h = (const float*)d_in[1];
    const float* d = (const float*)d_in[2];
    const float* T = (const float*)d_in[3];
    const float* b = (const float*)d_in[4];
    float* out = (float*)d_out;
    float* ws  = (float*)d_ws;

    int n  = in_sizes[0];
    int n4 = n / 4;

    build_kernel<<<1, 1024, 0, stream>>>(h, d, T, b, ws);
    // 4096 blocks x 256: 16 float4 iters/thread; LDS ~24.7 KB -> 6 blocks/CU
    // (24 waves/CU) for latency hiding.
    ps_act_kernel<<<4096, 256, 0, stream>>>(x, ws, out, n4);
}